// Round 1
// 221.985 us; speedup vs baseline: 1.0260x; 1.0260x over previous
//
#include <hip/hip_runtime.h>
#include <math.h>

#define RAD 20
#define KLEN 41
#define NH 1024
#define NW 2048
#define NHW (NH * NW)

// ---- Compile-time Gaussian-derivative weights (fp64, matches numpy) ----
struct KW { float w[KLEN]; };
constexpr double cexp_neg(double u) {  // exp(-u), 0 <= u <= 0.5
  double term = 1.0, sum = 1.0;
  for (int k = 1; k < 30; ++k) { term *= (-u) / (double)k; sum += term; }
  return sum;
}
constexpr KW make_kw() {
  KW r{};
  double ph[KLEN] = {};
  double s = 0.0;
  for (int i = 0; i < KLEN; ++i) {
    double d = (double)(i - RAD);
    double e = cexp_neg(d * d / 800.0);
    e = e * e; e = e * e; e = e * e; e = e * e;  // ^16
    ph[i] = e; s += e;
  }
  for (int i = 0; i < KLEN; ++i) {
    double d = (double)(i - RAD);
    r.w[i] = (float)((-d / 25.0) * (ph[i] / s) / 2.27);
  }
  return r;
}
static constexpr KW KWC = make_kw();

// Tap-major conv core, 8-accumulator form (used by k_dy).
template <int K>
__device__ __forceinline__ void tap(float s, float& r0, float& r1, float& r2,
                                    float& r3, float& r4, float& r5, float& r6,
                                    float& r7) {
  if constexpr (K - 0 >= 0 && K - 0 <= 40) r0 = fmaf(s, KWC.w[K - 0], r0);
  if constexpr (K - 1 >= 0 && K - 1 <= 40) r1 = fmaf(s, KWC.w[K - 1], r1);
  if constexpr (K - 2 >= 0 && K - 2 <= 40) r2 = fmaf(s, KWC.w[K - 2], r2);
  if constexpr (K - 3 >= 0 && K - 3 <= 40) r3 = fmaf(s, KWC.w[K - 3], r3);
  if constexpr (K - 4 >= 0 && K - 4 <= 40) r4 = fmaf(s, KWC.w[K - 4], r4);
  if constexpr (K - 5 >= 0 && K - 5 <= 40) r5 = fmaf(s, KWC.w[K - 5], r5);
  if constexpr (K - 6 >= 0 && K - 6 <= 40) r6 = fmaf(s, KWC.w[K - 6], r6);
  if constexpr (K - 7 >= 0 && K - 7 <= 40) r7 = fmaf(s, KWC.w[K - 7], r7);
}

#define R8 r0, r1, r2, r3, r4, r5, r6, r7

// 4-accumulator tap for the new k_dx (4 consecutive outputs per thread).
template <int K>
__device__ __forceinline__ void tap4(float s, float& r0, float& r1, float& r2,
                                     float& r3) {
  if constexpr (K - 0 >= 0 && K - 0 <= 40) r0 = fmaf(s, KWC.w[K - 0], r0);
  if constexpr (K - 1 >= 0 && K - 1 <= 40) r1 = fmaf(s, KWC.w[K - 1], r1);
  if constexpr (K - 2 >= 0 && K - 2 <= 40) r2 = fmaf(s, KWC.w[K - 2], r2);
  if constexpr (K - 3 >= 0 && K - 3 <= 40) r3 = fmaf(s, KWC.w[K - 3], r3);
}

template <int C>
__device__ __forceinline__ void chunk4x4(float4 a, float& r0, float& r1,
                                         float& r2, float& r3) {
  tap4<4 * C + 0>(a.x, r0, r1, r2, r3);
  tap4<4 * C + 1>(a.y, r0, r1, r2, r3);
  tap4<4 * C + 2>(a.z, r0, r1, r2, r3);
  tap4<4 * C + 3>(a.w, r0, r1, r2, r3);
}

// m_0 numerator: sum over pixels of ||m||_F (fp32 sqrt, fp64 accumulate).
__global__ __launch_bounds__(256) void k_reduce(const float* __restrict__ y,
                                                double* __restrict__ acc) {
  const int tid = blockIdx.x * blockDim.x + threadIdx.x;
  const int stride = gridDim.x * blockDim.x;
  double local = 0.0;
  for (int i = tid; i < NHW; i += stride) {
    float a = y[i];
    float b = y[i + NHW];
    float c = y[i + 2 * (size_t)NHW];
    float d = y[i + 3 * (size_t)NHW];
    local += (double)sqrtf(a * a + b * b + c * c + d * d);
  }
#pragma unroll
  for (int off = 32; off > 0; off >>= 1) local += __shfl_down(local, off, 64);
  __shared__ double smem[4];
  const int lane = threadIdx.x & 63;
  const int wid = threadIdx.x >> 6;
  if (lane == 0) smem[wid] = local;
  __syncthreads();
  if (threadIdx.x == 0) {
    double s = smem[0] + smem[1] + smem[2] + smem[3];
    atomicAdd(acc, s);
  }
}

// diffX, LDS-staged row + tap-major compute.
// Round-7 change: 4 consecutive outputs per thread (512 threads/block) so
// consecutive lanes read CONSECUTIVE 16B LDS granules (canonical dense
// ds_read_b128, conflict-free). The old 8-output form read at granule
// stride 2 -> lanes {l,l+4,l+8,...} shared one 4-bank group -> ~16-way
// serialization = 65% of kernel time (SQ_LDS_BANK_CONFLICT 2.17e7).
__global__ __launch_bounds__(512) void k_dx(const float* __restrict__ y,
                                            const float* __restrict__ v,
                                            float* __restrict__ ws) {
  __shared__ __align__(16) float row[NW + 2 * RAD];  // 2088 floats
  const int t = threadIdx.x;
  const int r = blockIdx.x;
  const int ch = blockIdx.y;  // 0..6 -> y0..y4, v0, v1
  const float* src = (ch < 5) ? (y + (size_t)ch * NHW) : (v + (size_t)(ch - 5) * NHW);
  const float* rp = src + (size_t)r * NW;

  // Stage: one dense float4 wave load per thread + reflect halo.
  const float4* rp4 = (const float4*)rp;
  float4 b0 = rp4[t];
  float4* row4 = (float4*)(row + RAD);  // 80B offset, 16B-aligned
  row4[t] = b0;
  if (t < RAD) {
    row[t] = rp[RAD - t];                // left reflect (no edge repeat)
    row[NW + RAD + t] = rp[NW - 2 - t];  // right reflect
  }
  __syncthreads();

  // Outputs x0=4t..4t+3; window = padded row[4t..4t+43] = granules t..t+10.
  // Lane l reads granule base+l+c -> dense, conflict-free.
  const float4* p = (const float4*)row + t;
  float r0 = 0.f, r1 = 0.f, r2 = 0.f, r3 = 0.f;
  chunk4x4<0>(p[0], r0, r1, r2, r3);
  chunk4x4<1>(p[1], r0, r1, r2, r3);
  chunk4x4<2>(p[2], r0, r1, r2, r3);
  chunk4x4<3>(p[3], r0, r1, r2, r3);
  chunk4x4<4>(p[4], r0, r1, r2, r3);
  chunk4x4<5>(p[5], r0, r1, r2, r3);
  chunk4x4<6>(p[6], r0, r1, r2, r3);
  chunk4x4<7>(p[7], r0, r1, r2, r3);
  chunk4x4<8>(p[8], r0, r1, r2, r3);
  chunk4x4<9>(p[9], r0, r1, r2, r3);
  chunk4x4<10>(p[10], r0, r1, r2, r3);

  float4 o;
  o.x = r0; o.y = r1; o.z = r2; o.w = r3;
  float4* dst = (float4*)(ws + (size_t)(7 + ch) * NHW + (size_t)r * NW) + t;
  *dst = o;
}

#define TW 64  // k_dy tile width (x)
#define TH 32  // k_dy output rows per block

// diffY, LDS-staged tile + tap-major compute. Wrap applied at staging.
__global__ __launch_bounds__(256) void k_dy(const float* __restrict__ y,
                                            const float* __restrict__ v,
                                            float* __restrict__ ws) {
  __shared__ float tile[(TH + 2 * RAD) * TW];  // 72*64 floats = 18432B
  const int lane = threadIdx.x & 63;
  const int wid = threadIdx.x >> 6;  // 0..3
  const int x0 = blockIdx.x * TW;
  const int yb = blockIdx.y * TH;
  const int ch = blockIdx.z;
  const float* src = (ch < 5) ? (y + (size_t)ch * NHW) : (v + (size_t)(ch - 5) * NHW);

  // Stage 72 rows: 18 INDEPENDENT coalesced loads into named regs (one vmcnt
  // drain), then 18 LDS writes. Wave w stages rows w, w+4, ..., w+68.
#define GLD(k) src[(size_t)(((yb - RAD + wid + 4 * (k)) + NH) & (NH - 1)) * NW + x0 + lane]
  float t0 = GLD(0), t1 = GLD(1), t2 = GLD(2), t3 = GLD(3), t4 = GLD(4);
  float t5 = GLD(5), t6 = GLD(6), t7 = GLD(7), t8 = GLD(8), t9 = GLD(9);
  float t10 = GLD(10), t11 = GLD(11), t12 = GLD(12), t13 = GLD(13);
  float t14 = GLD(14), t15 = GLD(15), t16 = GLD(16), t17 = GLD(17);
#define TST(k, val) tile[(wid + 4 * (k)) * TW + lane] = val;
  TST(0, t0)  TST(1, t1)  TST(2, t2)  TST(3, t3)  TST(4, t4)  TST(5, t5)
  TST(6, t6)  TST(7, t7)  TST(8, t8)  TST(9, t9)  TST(10, t10) TST(11, t11)
  TST(12, t12) TST(13, t13) TST(14, t14) TST(15, t15) TST(16, t16) TST(17, t17)
  __syncthreads();

  // Wave w produces output rows yb+8w..yb+8w+7 at column x0+lane.
  // Window = tile rows base..base+47 (base=8w); consume 4 rows at a time.
  const int base = wid * 8;
  float r0 = 0.f, r1 = 0.f, r2 = 0.f, r3 = 0.f;
  float r4 = 0.f, r5 = 0.f, r6 = 0.f, r7 = 0.f;
#define DYCHUNK(c)                                                   \
  {                                                                  \
    float s0 = tile[(base + 4 * (c) + 0) * TW + lane];               \
    float s1 = tile[(base + 4 * (c) + 1) * TW + lane];               \
    float s2 = tile[(base + 4 * (c) + 2) * TW + lane];               \
    float s3 = tile[(base + 4 * (c) + 3) * TW + lane];               \
    tap<4 * (c) + 0>(s0, R8);                                        \
    tap<4 * (c) + 1>(s1, R8);                                        \
    tap<4 * (c) + 2>(s2, R8);                                        \
    tap<4 * (c) + 3>(s3, R8);                                        \
  }
  DYCHUNK(0) DYCHUNK(1) DYCHUNK(2) DYCHUNK(3) DYCHUNK(4) DYCHUNK(5)
  DYCHUNK(6) DYCHUNK(7) DYCHUNK(8) DYCHUNK(9) DYCHUNK(10) DYCHUNK(11)

  float* dst = ws + (size_t)ch * NHW + (size_t)(yb + base) * NW + x0 + lane;
  dst[0] = r0;
  dst[(size_t)NW] = r1;
  dst[2 * (size_t)NW] = r2;
  dst[3 * (size_t)NW] = r3;
  dst[4 * (size_t)NW] = r4;
  dst[5 * (size_t)NW] = r5;
  dst[6 * (size_t)NW] = r6;
  dst[7 * (size_t)NW] = r7;
}

// Pointwise 2x2 tensor algebra. ws planes: [0..6]=dY(ch), [7..13]=dX(ch).
__global__ __launch_bounds__(256) void k_final(
    const float* __restrict__ y, const float* __restrict__ v,
    const float* __restrict__ gds, const float* __restrict__ cadc,
    const float* __restrict__ myoc, const float* __restrict__ ws,
    const double* __restrict__ acc, float* __restrict__ out) {
  const size_t i = (size_t)blockIdx.x * blockDim.x + threadIdx.x;
  if (i >= NHW) return;

  const float m0 = (float)(acc[0] / (double)NHW);
  const float cad0 = fmaxf(cadc[0], 0.f);
  const float cad1 = fmaxf(cadc[1], 0.f);
  const float cad2 = fmaxf(cadc[2], 0.f);
  const float my0 = fmaxf(myoc[0], 0.f);
  const float my1 = fmaxf(myoc[1], 0.f);
  const float my2 = fmaxf(myoc[2], 0.f);
  const float my3 = fmaxf(myoc[3], 0.f);
  const float my4 = fmaxf(myoc[4], 0.f);

  const float m00 = y[i];
  const float m01 = y[i + (size_t)NHW];
  const float m10 = y[i + 2 * (size_t)NHW];
  const float m11 = y[i + 3 * (size_t)NHW];
  const float c = y[i + 4 * (size_t)NHW];
  const float v0 = v[i];
  const float v1 = v[i + (size_t)NHW];
  const float g = gds[i];

  const float dY_m00 = ws[i];
  const float dY_m01 = ws[i + (size_t)NHW];
  const float dY_m10 = ws[i + 2 * (size_t)NHW];
  const float dY_m11 = ws[i + 3 * (size_t)NHW];
  const float dY_c = ws[i + 4 * (size_t)NHW];
  const float dY_v0 = ws[i + 5 * (size_t)NHW];
  const float dY_v1 = ws[i + 6 * (size_t)NHW];
  const float dX_m00 = ws[i + 7 * (size_t)NHW];
  const float dX_m01 = ws[i + 8 * (size_t)NHW];
  const float dX_m10 = ws[i + 9 * (size_t)NHW];
  const float dX_m11 = ws[i + 10 * (size_t)NHW];
  const float dX_c = ws[i + 11 * (size_t)NHW];
  const float dX_v0 = ws[i + 12 * (size_t)NHW];
  const float dX_v1 = ws[i + 13 * (size_t)NHW];

  // gv[i][j] = d_j v_i ; j=0 -> Y, j=1 -> X
  const float gv00 = dY_v0, gv01 = dX_v0, gv10 = dY_v1, gv11 = dX_v1;
  const float ww = -0.5f * (gv01 - gv10);
  const float E00 = gv00, E11 = gv11;
  const float E01 = 0.5f * (gv01 + gv10);
  const float E10 = E01;

  const float trm = m00 + m11;
  const float dev00 = m00 - 0.5f * trm;
  const float dev01 = m01;
  const float dev10 = m10;
  const float dev11 = m11 - 0.5f * trm;
  const float dmag_sq = dev00 * dev00 + dev01 * dev01 + dev10 * dev10 + dev11 * dev11;
  const float dm = sqrtf(dmag_sq);
  const float dm2 = dm * dm;  // reference squares the sqrt
  const float devE = dev00 * E00 + dev01 * E01 + dev10 * E10 + dev11 * E11;
  const float sg = (devE > 0.f) ? 1.f : ((devE < 0.f) ? -1.f : 0.f);
  const float coef = sg * devE / dm2;
  const float sc = 0.5f * dm / m0;

  const float Ea00 = (E00 - coef * dev00) * sc;
  const float Ea01 = (E01 - coef * dev01) * sc;
  const float Ea10 = (E10 - coef * dev10) * sc;
  const float Ea11 = (E11 - coef * dev11) * sc;
  const float Ep00 = E00 - Ea00;
  const float Ep01 = E01 - Ea01;
  const float Ep10 = E10 - Ea10;
  const float Ep11 = E11 - Ea11;

  // mE = m*Ep + Ep*m
  const float mE00 = (m00 * Ep00 + m01 * Ep10) + (Ep00 * m00 + Ep01 * m10);
  const float mE01 = (m00 * Ep01 + m01 * Ep11) + (Ep00 * m01 + Ep01 * m11);
  const float mE10 = (m10 * Ep00 + m11 * Ep10) + (Ep10 * m00 + Ep11 * m10);
  const float mE11 = (m10 * Ep01 + m11 * Ep11) + (Ep10 * m01 + Ep11 * m11);

  const float divv = gv00 + gv11;
  const float cdot = -(v0 * dY_c + v1 * dX_c) - cad0 * c + cad1 * c * divv + cad2 * g;

  const float md00 = -(v0 * dY_m00 + v1 * dX_m00) - ww * m10 - ww * m01 - my0 * m00 +
                     my1 * mE00 - my2 * c * mE00 + my3 * trm + my4 * trm * m00;
  const float md01 = -(v0 * dY_m01 + v1 * dX_m01) - ww * m11 + ww * m00 - my0 * m01 +
                     my1 * mE01 - my2 * c * mE01 + my4 * trm * m01;
  const float md10 = -(v0 * dY_m10 + v1 * dX_m10) + ww * m00 - ww * m11 - my0 * m10 +
                     my1 * mE10 - my2 * c * mE10 + my4 * trm * m10;
  const float md11 = -(v0 * dY_m11 + v1 * dX_m11) + ww * m01 + ww * m10 - my0 * m11 +
                     my1 * mE11 - my2 * c * mE11 + my4 * trm * m11;

  out[i] = md00;
  out[i + (size_t)NHW] = md01;
  out[i + 2 * (size_t)NHW] = md10;
  out[i + 3 * (size_t)NHW] = md11;
  out[i + 4 * (size_t)NHW] = cdot;
}

extern "C" void kernel_launch(void* const* d_in, const int* in_sizes, int n_in,
                              void* d_out, int out_size, void* d_ws, size_t ws_size,
                              hipStream_t stream) {
  (void)in_sizes; (void)n_in; (void)out_size; (void)ws_size;
  const float* y = (const float*)d_in[0];
  const float* v = (const float*)d_in[1];
  const float* gds = (const float*)d_in[2];
  const float* cadc = (const float*)d_in[3];
  const float* myoc = (const float*)d_in[4];
  float* out = (float*)d_out;

  double* acc = (double*)d_ws;                       // 8B accumulator
  float* planes = (float*)((char*)d_ws + 512);       // 14 x NHW fp32 planes

  hipMemsetAsync(acc, 0, sizeof(double), stream);
  k_reduce<<<dim3(1024), dim3(256), 0, stream>>>(y, acc);
  k_dx<<<dim3(NH, 7), dim3(512), 0, stream>>>(y, v, planes);
  k_dy<<<dim3(NW / TW, NH / TH, 7), dim3(256), 0, stream>>>(y, v, planes);
  k_final<<<dim3(NHW / 256), dim3(256), 0, stream>>>(y, v, gds, cadc, myoc, planes, acc, out);
}

// Round 2
// 202.059 us; speedup vs baseline: 1.1272x; 1.0986x over previous
//
#include <hip/hip_runtime.h>
#include <math.h>

#define RAD 20
#define KLEN 41
#define NH 1024
#define NW 2048
#define NHW (NH * NW)

// ---- Compile-time Gaussian-derivative weights (fp64, matches numpy) ----
struct KW { float w[KLEN]; };
constexpr double cexp_neg(double u) {  // exp(-u), 0 <= u <= 0.5
  double term = 1.0, sum = 1.0;
  for (int k = 1; k < 30; ++k) { term *= (-u) / (double)k; sum += term; }
  return sum;
}
constexpr KW make_kw() {
  KW r{};
  double ph[KLEN] = {};
  double s = 0.0;
  for (int i = 0; i < KLEN; ++i) {
    double d = (double)(i - RAD);
    double e = cexp_neg(d * d / 800.0);
    e = e * e; e = e * e; e = e * e; e = e * e;  // ^16
    ph[i] = e; s += e;
  }
  for (int i = 0; i < KLEN; ++i) {
    double d = (double)(i - RAD);
    r.w[i] = (float)((-d / 25.0) * (ph[i] / s) / 2.27);
  }
  return r;
}
static constexpr KW KWC = make_kw();

// Tap-major conv core, 8-accumulator form (k_dx and k_dy).
template <int K>
__device__ __forceinline__ void tap(float s, float& r0, float& r1, float& r2,
                                    float& r3, float& r4, float& r5, float& r6,
                                    float& r7) {
  if constexpr (K - 0 >= 0 && K - 0 <= 40) r0 = fmaf(s, KWC.w[K - 0], r0);
  if constexpr (K - 1 >= 0 && K - 1 <= 40) r1 = fmaf(s, KWC.w[K - 1], r1);
  if constexpr (K - 2 >= 0 && K - 2 <= 40) r2 = fmaf(s, KWC.w[K - 2], r2);
  if constexpr (K - 3 >= 0 && K - 3 <= 40) r3 = fmaf(s, KWC.w[K - 3], r3);
  if constexpr (K - 4 >= 0 && K - 4 <= 40) r4 = fmaf(s, KWC.w[K - 4], r4);
  if constexpr (K - 5 >= 0 && K - 5 <= 40) r5 = fmaf(s, KWC.w[K - 5], r5);
  if constexpr (K - 6 >= 0 && K - 6 <= 40) r6 = fmaf(s, KWC.w[K - 6], r6);
  if constexpr (K - 7 >= 0 && K - 7 <= 40) r7 = fmaf(s, KWC.w[K - 7], r7);
}

#define R8 r0, r1, r2, r3, r4, r5, r6, r7

// m_0 numerator: sum over pixels of ||m||_F (fp32 sqrt, fp64 accumulate).
__global__ __launch_bounds__(256) void k_reduce(const float* __restrict__ y,
                                                double* __restrict__ acc) {
  const int tid = blockIdx.x * blockDim.x + threadIdx.x;
  const int stride = gridDim.x * blockDim.x;
  double local = 0.0;
  for (int i = tid; i < NHW; i += stride) {
    float a = y[i];
    float b = y[i + NHW];
    float c = y[i + 2 * (size_t)NHW];
    float d = y[i + 3 * (size_t)NHW];
    local += (double)sqrtf(a * a + b * b + c * c + d * d);
  }
#pragma unroll
  for (int off = 32; off > 0; off >>= 1) local += __shfl_down(local, off, 64);
  __shared__ double smem[4];
  const int lane = threadIdx.x & 63;
  const int wid = threadIdx.x >> 6;
  if (lane == 0) smem[wid] = local;
  __syncthreads();
  if (threadIdx.x == 0) {
    double s = smem[0] + smem[1] + smem[2] + smem[3];
    atomicAdd(acc, s);
  }
}

// diffX with swizzled-LDS scalar reads.
// Round-8 lesson: dense wave64 ds_read_b128 still serializes ~4x on gfx950
// (1.72e7 conflict cycles over 631k reads, ~27 extra cyc each). The only
// pattern empirically conflict-clean here is k_dy's: scalar b32, lane-stride
// 4B. To get that WITH 8-output reuse, store the padded row swizzled:
//   addr(x) = x + (x>>6)
// Then for a fixed tap k, thread t reads x = 8t+k -> bank = 8(t&3)+(t>>3),
// exactly 2 lanes per bank (t, t+4) = free (m136). 48 scalar reads / 8
// outputs = 24B/output LDS traffic, all <=2-way.
__global__ __launch_bounds__(256) void k_dx(const float* __restrict__ y,
                                            const float* __restrict__ v,
                                            float* __restrict__ ws) {
  __shared__ float row[2120];  // 2088 padded floats, swizzle-expanded
  const int t = threadIdx.x;
  const int r = blockIdx.x;
  const int ch = blockIdx.y;  // 0..6 -> y0..y4, v0, v1
  const float* src = (ch < 5) ? (y + (size_t)ch * NHW) : (v + (size_t)(ch - 5) * NHW);
  const float* rp = src + (size_t)r * NW;

#define SWZ(i) ((i) + ((i) >> 6))
#define ST(i, val) { const int ii_ = (i); row[SWZ(ii_)] = (val); }

  // Stage: two dense float4 global loads per thread, scattered scalar LDS
  // writes (swizzled). Write pattern is <=2-way per bank.
  const float4* rp4 = (const float4*)rp;
  float4 b0 = rp4[t];
  float4 b1 = rp4[t + 256];
  ST(RAD + 4 * t + 0, b0.x)
  ST(RAD + 4 * t + 1, b0.y)
  ST(RAD + 4 * t + 2, b0.z)
  ST(RAD + 4 * t + 3, b0.w)
  ST(RAD + 4 * (t + 256) + 0, b1.x)
  ST(RAD + 4 * (t + 256) + 1, b1.y)
  ST(RAD + 4 * (t + 256) + 2, b1.z)
  ST(RAD + 4 * (t + 256) + 3, b1.w)
  if (t < RAD) {
    ST(t, rp[RAD - t])                // left reflect (no edge repeat)
    ST(NW + RAD + t, rp[NW - 2 - t])  // right reflect
  }
  __syncthreads();

  // Outputs x0=8t..8t+7; window = padded[8t .. 8t+47], read one scalar at a
  // time through the swizzle, tap-major into 8 accumulators.
  const int xb = 8 * t;
  float r0 = 0.f, r1 = 0.f, r2 = 0.f, r3 = 0.f;
  float r4 = 0.f, r5 = 0.f, r6 = 0.f, r7 = 0.f;
#define RD(k) { const int x_ = xb + (k); float s_ = row[SWZ(x_)]; tap<(k)>(s_, R8); }
  RD(0)  RD(1)  RD(2)  RD(3)  RD(4)  RD(5)  RD(6)  RD(7)
  RD(8)  RD(9)  RD(10) RD(11) RD(12) RD(13) RD(14) RD(15)
  RD(16) RD(17) RD(18) RD(19) RD(20) RD(21) RD(22) RD(23)
  RD(24) RD(25) RD(26) RD(27) RD(28) RD(29) RD(30) RD(31)
  RD(32) RD(33) RD(34) RD(35) RD(36) RD(37) RD(38) RD(39)
  RD(40) RD(41) RD(42) RD(43) RD(44) RD(45) RD(46) RD(47)
#undef RD

  float4 o0, o1;
  o0.x = r0; o0.y = r1; o0.z = r2; o0.w = r3;
  o1.x = r4; o1.y = r5; o1.z = r6; o1.w = r7;
  float4* dst = (float4*)(ws + (size_t)(7 + ch) * NHW + (size_t)r * NW + xb);
  dst[0] = o0;
  dst[1] = o1;
}

#define TW 64  // k_dy tile width (x)
#define TH 32  // k_dy output rows per block

// diffY, LDS-staged tile + tap-major compute. Wrap applied at staging.
__global__ __launch_bounds__(256) void k_dy(const float* __restrict__ y,
                                            const float* __restrict__ v,
                                            float* __restrict__ ws) {
  __shared__ float tile[(TH + 2 * RAD) * TW];  // 72*64 floats = 18432B
  const int lane = threadIdx.x & 63;
  const int wid = threadIdx.x >> 6;  // 0..3
  const int x0 = blockIdx.x * TW;
  const int yb = blockIdx.y * TH;
  const int ch = blockIdx.z;
  const float* src = (ch < 5) ? (y + (size_t)ch * NHW) : (v + (size_t)(ch - 5) * NHW);

  // Stage 72 rows: 18 INDEPENDENT coalesced loads into named regs (one vmcnt
  // drain), then 18 LDS writes. Wave w stages rows w, w+4, ..., w+68.
#define GLD(k) src[(size_t)(((yb - RAD + wid + 4 * (k)) + NH) & (NH - 1)) * NW + x0 + lane]
  float t0 = GLD(0), t1 = GLD(1), t2 = GLD(2), t3 = GLD(3), t4 = GLD(4);
  float t5 = GLD(5), t6 = GLD(6), t7 = GLD(7), t8 = GLD(8), t9 = GLD(9);
  float t10 = GLD(10), t11 = GLD(11), t12 = GLD(12), t13 = GLD(13);
  float t14 = GLD(14), t15 = GLD(15), t16 = GLD(16), t17 = GLD(17);
#define TST(k, val) tile[(wid + 4 * (k)) * TW + lane] = val;
  TST(0, t0)  TST(1, t1)  TST(2, t2)  TST(3, t3)  TST(4, t4)  TST(5, t5)
  TST(6, t6)  TST(7, t7)  TST(8, t8)  TST(9, t9)  TST(10, t10) TST(11, t11)
  TST(12, t12) TST(13, t13) TST(14, t14) TST(15, t15) TST(16, t16) TST(17, t17)
  __syncthreads();

  // Wave w produces output rows yb+8w..yb+8w+7 at column x0+lane.
  // Window = tile rows base..base+47 (base=8w); consume 4 rows at a time.
  const int base = wid * 8;
  float r0 = 0.f, r1 = 0.f, r2 = 0.f, r3 = 0.f;
  float r4 = 0.f, r5 = 0.f, r6 = 0.f, r7 = 0.f;
#define DYCHUNK(c)                                                   \
  {                                                                  \
    float s0 = tile[(base + 4 * (c) + 0) * TW + lane];               \
    float s1 = tile[(base + 4 * (c) + 1) * TW + lane];               \
    float s2 = tile[(base + 4 * (c) + 2) * TW + lane];               \
    float s3 = tile[(base + 4 * (c) + 3) * TW + lane];               \
    tap<4 * (c) + 0>(s0, R8);                                        \
    tap<4 * (c) + 1>(s1, R8);                                        \
    tap<4 * (c) + 2>(s2, R8);                                        \
    tap<4 * (c) + 3>(s3, R8);                                        \
  }
  DYCHUNK(0) DYCHUNK(1) DYCHUNK(2) DYCHUNK(3) DYCHUNK(4) DYCHUNK(5)
  DYCHUNK(6) DYCHUNK(7) DYCHUNK(8) DYCHUNK(9) DYCHUNK(10) DYCHUNK(11)

  float* dst = ws + (size_t)ch * NHW + (size_t)(yb + base) * NW + x0 + lane;
  dst[0] = r0;
  dst[(size_t)NW] = r1;
  dst[2 * (size_t)NW] = r2;
  dst[3 * (size_t)NW] = r3;
  dst[4 * (size_t)NW] = r4;
  dst[5 * (size_t)NW] = r5;
  dst[6 * (size_t)NW] = r6;
  dst[7 * (size_t)NW] = r7;
}

// Pointwise 2x2 tensor algebra. ws planes: [0..6]=dY(ch), [7..13]=dX(ch).
__global__ __launch_bounds__(256) void k_final(
    const float* __restrict__ y, const float* __restrict__ v,
    const float* __restrict__ gds, const float* __restrict__ cadc,
    const float* __restrict__ myoc, const float* __restrict__ ws,
    const double* __restrict__ acc, float* __restrict__ out) {
  const size_t i = (size_t)blockIdx.x * blockDim.x + threadIdx.x;
  if (i >= NHW) return;

  const float m0 = (float)(acc[0] / (double)NHW);
  const float cad0 = fmaxf(cadc[0], 0.f);
  const float cad1 = fmaxf(cadc[1], 0.f);
  const float cad2 = fmaxf(cadc[2], 0.f);
  const float my0 = fmaxf(myoc[0], 0.f);
  const float my1 = fmaxf(myoc[1], 0.f);
  const float my2 = fmaxf(myoc[2], 0.f);
  const float my3 = fmaxf(myoc[3], 0.f);
  const float my4 = fmaxf(myoc[4], 0.f);

  const float m00 = y[i];
  const float m01 = y[i + (size_t)NHW];
  const float m10 = y[i + 2 * (size_t)NHW];
  const float m11 = y[i + 3 * (size_t)NHW];
  const float c = y[i + 4 * (size_t)NHW];
  const float v0 = v[i];
  const float v1 = v[i + (size_t)NHW];
  const float g = gds[i];

  const float dY_m00 = ws[i];
  const float dY_m01 = ws[i + (size_t)NHW];
  const float dY_m10 = ws[i + 2 * (size_t)NHW];
  const float dY_m11 = ws[i + 3 * (size_t)NHW];
  const float dY_c = ws[i + 4 * (size_t)NHW];
  const float dY_v0 = ws[i + 5 * (size_t)NHW];
  const float dY_v1 = ws[i + 6 * (size_t)NHW];
  const float dX_m00 = ws[i + 7 * (size_t)NHW];
  const float dX_m01 = ws[i + 8 * (size_t)NHW];
  const float dX_m10 = ws[i + 9 * (size_t)NHW];
  const float dX_m11 = ws[i + 10 * (size_t)NHW];
  const float dX_c = ws[i + 11 * (size_t)NHW];
  const float dX_v0 = ws[i + 12 * (size_t)NHW];
  const float dX_v1 = ws[i + 13 * (size_t)NHW];

  // gv[i][j] = d_j v_i ; j=0 -> Y, j=1 -> X
  const float gv00 = dY_v0, gv01 = dX_v0, gv10 = dY_v1, gv11 = dX_v1;
  const float ww = -0.5f * (gv01 - gv10);
  const float E00 = gv00, E11 = gv11;
  const float E01 = 0.5f * (gv01 + gv10);
  const float E10 = E01;

  const float trm = m00 + m11;
  const float dev00 = m00 - 0.5f * trm;
  const float dev01 = m01;
  const float dev10 = m10;
  const float dev11 = m11 - 0.5f * trm;
  const float dmag_sq = dev00 * dev00 + dev01 * dev01 + dev10 * dev10 + dev11 * dev11;
  const float dm = sqrtf(dmag_sq);
  const float dm2 = dm * dm;  // reference squares the sqrt
  const float devE = dev00 * E00 + dev01 * E01 + dev10 * E10 + dev11 * E11;
  const float sg = (devE > 0.f) ? 1.f : ((devE < 0.f) ? -1.f : 0.f);
  const float coef = sg * devE / dm2;
  const float sc = 0.5f * dm / m0;

  const float Ea00 = (E00 - coef * dev00) * sc;
  const float Ea01 = (E01 - coef * dev01) * sc;
  const float Ea10 = (E10 - coef * dev10) * sc;
  const float Ea11 = (E11 - coef * dev11) * sc;
  const float Ep00 = E00 - Ea00;
  const float Ep01 = E01 - Ea01;
  const float Ep10 = E10 - Ea10;
  const float Ep11 = E11 - Ea11;

  // mE = m*Ep + Ep*m
  const float mE00 = (m00 * Ep00 + m01 * Ep10) + (Ep00 * m00 + Ep01 * m10);
  const float mE01 = (m00 * Ep01 + m01 * Ep11) + (Ep00 * m01 + Ep01 * m11);
  const float mE10 = (m10 * Ep00 + m11 * Ep10) + (Ep10 * m00 + Ep11 * m10);
  const float mE11 = (m10 * Ep01 + m11 * Ep11) + (Ep10 * m01 + Ep11 * m11);

  const float divv = gv00 + gv11;
  const float cdot = -(v0 * dY_c + v1 * dX_c) - cad0 * c + cad1 * c * divv + cad2 * g;

  const float md00 = -(v0 * dY_m00 + v1 * dX_m00) - ww * m10 - ww * m01 - my0 * m00 +
                     my1 * mE00 - my2 * c * mE00 + my3 * trm + my4 * trm * m00;
  const float md01 = -(v0 * dY_m01 + v1 * dX_m01) - ww * m11 + ww * m00 - my0 * m01 +
                     my1 * mE01 - my2 * c * mE01 + my4 * trm * m01;
  const float md10 = -(v0 * dY_m10 + v1 * dX_m10) + ww * m00 - ww * m11 - my0 * m10 +
                     my1 * mE10 - my2 * c * mE10 + my4 * trm * m10;
  const float md11 = -(v0 * dY_m11 + v1 * dX_m11) + ww * m01 + ww * m10 - my0 * m11 +
                     my1 * mE11 - my2 * c * mE11 + my4 * trm * m11;

  out[i] = md00;
  out[i + (size_t)NHW] = md01;
  out[i + 2 * (size_t)NHW] = md10;
  out[i + 3 * (size_t)NHW] = md11;
  out[i + 4 * (size_t)NHW] = cdot;
}

extern "C" void kernel_launch(void* const* d_in, const int* in_sizes, int n_in,
                              void* d_out, int out_size, void* d_ws, size_t ws_size,
                              hipStream_t stream) {
  (void)in_sizes; (void)n_in; (void)out_size; (void)ws_size;
  const float* y = (const float*)d_in[0];
  const float* v = (const float*)d_in[1];
  const float* gds = (const float*)d_in[2];
  const float* cadc = (const float*)d_in[3];
  const float* myoc = (const float*)d_in[4];
  float* out = (float*)d_out;

  double* acc = (double*)d_ws;                       // 8B accumulator
  float* planes = (float*)((char*)d_ws + 512);       // 14 x NHW fp32 planes

  hipMemsetAsync(acc, 0, sizeof(double), stream);
  k_reduce<<<dim3(1024), dim3(256), 0, stream>>>(y, acc);
  k_dx<<<dim3(NH, 7), dim3(256), 0, stream>>>(y, v, planes);
  k_dy<<<dim3(NW / TW, NH / TH, 7), dim3(256), 0, stream>>>(y, v, planes);
  k_final<<<dim3(NHW / 256), dim3(256), 0, stream>>>(y, v, gds, cadc, myoc, planes, acc, out);
}

// Round 4
// 196.440 us; speedup vs baseline: 1.1594x; 1.0286x over previous
//
#include <hip/hip_runtime.h>
#include <math.h>

#define RAD 20
#define KLEN 41
#define NH 1024
#define NW 2048
#define NHW (NH * NW)

// ---- Compile-time Gaussian-derivative weights (fp64, matches numpy) ----
struct KW { float w[KLEN]; };
constexpr double cexp_neg(double u) {  // exp(-u), 0 <= u <= 0.5
  double term = 1.0, sum = 1.0;
  for (int k = 1; k < 30; ++k) { term *= (-u) / (double)k; sum += term; }
  return sum;
}
constexpr KW make_kw() {
  KW r{};
  double ph[KLEN] = {};
  double s = 0.0;
  for (int i = 0; i < KLEN; ++i) {
    double d = (double)(i - RAD);
    double e = cexp_neg(d * d / 800.0);
    e = e * e; e = e * e; e = e * e; e = e * e;  // ^16
    ph[i] = e; s += e;
  }
  for (int i = 0; i < KLEN; ++i) {
    double d = (double)(i - RAD);
    r.w[i] = (float)((-d / 25.0) * (ph[i] / s) / 2.27);
  }
  return r;
}
static constexpr KW KWC = make_kw();

// Tap-major conv core, 8-accumulator form (k_dx and k_dy).
template <int K>
__device__ __forceinline__ void tap(float s, float& r0, float& r1, float& r2,
                                    float& r3, float& r4, float& r5, float& r6,
                                    float& r7) {
  if constexpr (K - 0 >= 0 && K - 0 <= 40) r0 = fmaf(s, KWC.w[K - 0], r0);
  if constexpr (K - 1 >= 0 && K - 1 <= 40) r1 = fmaf(s, KWC.w[K - 1], r1);
  if constexpr (K - 2 >= 0 && K - 2 <= 40) r2 = fmaf(s, KWC.w[K - 2], r2);
  if constexpr (K - 3 >= 0 && K - 3 <= 40) r3 = fmaf(s, KWC.w[K - 3], r3);
  if constexpr (K - 4 >= 0 && K - 4 <= 40) r4 = fmaf(s, KWC.w[K - 4], r4);
  if constexpr (K - 5 >= 0 && K - 5 <= 40) r5 = fmaf(s, KWC.w[K - 5], r5);
  if constexpr (K - 6 >= 0 && K - 6 <= 40) r6 = fmaf(s, KWC.w[K - 6], r6);
  if constexpr (K - 7 >= 0 && K - 7 <= 40) r7 = fmaf(s, KWC.w[K - 7], r7);
}

#define R8 r0, r1, r2, r3, r4, r5, r6, r7

// Compile-time component select (j is always an unrolled constant -> SROA).
__device__ __forceinline__ float comp4(const float4& a, int j) {
  return (j == 0) ? a.x : (j == 1) ? a.y : (j == 2) ? a.z : a.w;
}
__device__ __forceinline__ void setcomp4(float4& a, int j, float val) {
  if (j == 0) a.x = val;
  else if (j == 1) a.y = val;
  else if (j == 2) a.z = val;
  else a.w = val;
}

// m_0 numerator: sum over pixels of ||m||_F (fp32 sqrt, fp64 accumulate).
// float4-vectorized loads (G13).
__global__ __launch_bounds__(256) void k_reduce(const float* __restrict__ y,
                                                double* __restrict__ acc) {
  const int tid = blockIdx.x * blockDim.x + threadIdx.x;
  const int stride = gridDim.x * blockDim.x;
  double local = 0.0;
  for (int q = tid; q < NHW / 4; q += stride) {
    float4 a = ((const float4*)y)[q];
    float4 b = ((const float4*)(y + NHW))[q];
    float4 c = ((const float4*)(y + 2 * (size_t)NHW))[q];
    float4 d = ((const float4*)(y + 3 * (size_t)NHW))[q];
    local += (double)sqrtf(a.x * a.x + b.x * b.x + c.x * c.x + d.x * d.x);
    local += (double)sqrtf(a.y * a.y + b.y * b.y + c.y * c.y + d.y * d.y);
    local += (double)sqrtf(a.z * a.z + b.z * b.z + c.z * c.z + d.z * d.z);
    local += (double)sqrtf(a.w * a.w + b.w * b.w + c.w * c.w + d.w * d.w);
  }
#pragma unroll
  for (int off = 32; off > 0; off >>= 1) local += __shfl_down(local, off, 64);
  __shared__ double smem[4];
  const int lane = threadIdx.x & 63;
  const int wid = threadIdx.x >> 6;
  if (lane == 0) smem[wid] = local;
  __syncthreads();
  if (threadIdx.x == 0) {
    double s = smem[0] + smem[1] + smem[2] + smem[3];
    atomicAdd(acc, s);
  }
}

// diffX with swizzled-LDS scalar reads (round-8 pattern: addr(x)=x+(x>>6),
// <=2-way banks on every read/write; conflicts eliminated vs b128 forms).
__global__ __launch_bounds__(256) void k_dx(const float* __restrict__ y,
                                            const float* __restrict__ v,
                                            float* __restrict__ ws) {
  __shared__ float row[2120];  // 2088 padded floats, swizzle-expanded
  const int t = threadIdx.x;
  const int r = blockIdx.x;
  const int ch = blockIdx.y;  // 0..6 -> y0..y4, v0, v1
  const float* src = (ch < 5) ? (y + (size_t)ch * NHW) : (v + (size_t)(ch - 5) * NHW);
  const float* rp = src + (size_t)r * NW;

#define SWZ(i) ((i) + ((i) >> 6))
#define ST(i, val) { const int ii_ = (i); row[SWZ(ii_)] = (val); }

  const float4* rp4 = (const float4*)rp;
  float4 b0 = rp4[t];
  float4 b1 = rp4[t + 256];
  ST(RAD + 4 * t + 0, b0.x)
  ST(RAD + 4 * t + 1, b0.y)
  ST(RAD + 4 * t + 2, b0.z)
  ST(RAD + 4 * t + 3, b0.w)
  ST(RAD + 4 * (t + 256) + 0, b1.x)
  ST(RAD + 4 * (t + 256) + 1, b1.y)
  ST(RAD + 4 * (t + 256) + 2, b1.z)
  ST(RAD + 4 * (t + 256) + 3, b1.w)
  if (t < RAD) {
    ST(t, rp[RAD - t])                // left reflect (no edge repeat)
    ST(NW + RAD + t, rp[NW - 2 - t])  // right reflect
  }
  __syncthreads();

  const int xb = 8 * t;
  float r0 = 0.f, r1 = 0.f, r2 = 0.f, r3 = 0.f;
  float r4 = 0.f, r5 = 0.f, r6 = 0.f, r7 = 0.f;
#define RD(k) { const int x_ = xb + (k); float s_ = row[SWZ(x_)]; tap<(k)>(s_, R8); }
  RD(0)  RD(1)  RD(2)  RD(3)  RD(4)  RD(5)  RD(6)  RD(7)
  RD(8)  RD(9)  RD(10) RD(11) RD(12) RD(13) RD(14) RD(15)
  RD(16) RD(17) RD(18) RD(19) RD(20) RD(21) RD(22) RD(23)
  RD(24) RD(25) RD(26) RD(27) RD(28) RD(29) RD(30) RD(31)
  RD(32) RD(33) RD(34) RD(35) RD(36) RD(37) RD(38) RD(39)
  RD(40) RD(41) RD(42) RD(43) RD(44) RD(45) RD(46) RD(47)
#undef RD

  float4 o0, o1;
  o0.x = r0; o0.y = r1; o0.z = r2; o0.w = r3;
  o1.x = r4; o1.y = r5; o1.z = r6; o1.w = r7;
  float4* dst = (float4*)(ws + (size_t)(7 + ch) * NHW + (size_t)r * NW + xb);
  dst[0] = o0;
  dst[1] = o1;
}

#define TW 64  // k_dy tile width (x)
#define TH 32  // k_dy output rows per block

// diffY, LDS-staged tile + tap-major compute. Wrap applied at staging.
__global__ __launch_bounds__(256) void k_dy(const float* __restrict__ y,
                                            const float* __restrict__ v,
                                            float* __restrict__ ws) {
  __shared__ float tile[(TH + 2 * RAD) * TW];  // 72*64 floats = 18432B
  const int lane = threadIdx.x & 63;
  const int wid = threadIdx.x >> 6;  // 0..3
  const int x0 = blockIdx.x * TW;
  const int yb = blockIdx.y * TH;
  const int ch = blockIdx.z;
  const float* src = (ch < 5) ? (y + (size_t)ch * NHW) : (v + (size_t)(ch - 5) * NHW);

#define GLD(k) src[(size_t)(((yb - RAD + wid + 4 * (k)) + NH) & (NH - 1)) * NW + x0 + lane]
  float t0 = GLD(0), t1 = GLD(1), t2 = GLD(2), t3 = GLD(3), t4 = GLD(4);
  float t5 = GLD(5), t6 = GLD(6), t7 = GLD(7), t8 = GLD(8), t9 = GLD(9);
  float t10 = GLD(10), t11 = GLD(11), t12 = GLD(12), t13 = GLD(13);
  float t14 = GLD(14), t15 = GLD(15), t16 = GLD(16), t17 = GLD(17);
#define TST(k, val) tile[(wid + 4 * (k)) * TW + lane] = val;
  TST(0, t0)  TST(1, t1)  TST(2, t2)  TST(3, t3)  TST(4, t4)  TST(5, t5)
  TST(6, t6)  TST(7, t7)  TST(8, t8)  TST(9, t9)  TST(10, t10) TST(11, t11)
  TST(12, t12) TST(13, t13) TST(14, t14) TST(15, t15) TST(16, t16) TST(17, t17)
  __syncthreads();

  const int base = wid * 8;
  float r0 = 0.f, r1 = 0.f, r2 = 0.f, r3 = 0.f;
  float r4 = 0.f, r5 = 0.f, r6 = 0.f, r7 = 0.f;
#define DYCHUNK(c)                                                   \
  {                                                                  \
    float s0 = tile[(base + 4 * (c) + 0) * TW + lane];               \
    float s1 = tile[(base + 4 * (c) + 1) * TW + lane];               \
    float s2 = tile[(base + 4 * (c) + 2) * TW + lane];               \
    float s3 = tile[(base + 4 * (c) + 3) * TW + lane];               \
    tap<4 * (c) + 0>(s0, R8);                                        \
    tap<4 * (c) + 1>(s1, R8);                                        \
    tap<4 * (c) + 2>(s2, R8);                                        \
    tap<4 * (c) + 3>(s3, R8);                                        \
  }
  DYCHUNK(0) DYCHUNK(1) DYCHUNK(2) DYCHUNK(3) DYCHUNK(4) DYCHUNK(5)
  DYCHUNK(6) DYCHUNK(7) DYCHUNK(8) DYCHUNK(9) DYCHUNK(10) DYCHUNK(11)

  float* dst = ws + (size_t)ch * NHW + (size_t)(yb + base) * NW + x0 + lane;
  dst[0] = r0;
  dst[(size_t)NW] = r1;
  dst[2 * (size_t)NW] = r2;
  dst[3 * (size_t)NW] = r3;
  dst[4 * (size_t)NW] = r4;
  dst[5 * (size_t)NW] = r5;
  dst[6 * (size_t)NW] = r6;
  dst[7 * (size_t)NW] = r7;
}

// Pointwise 2x2 tensor algebra, float4-vectorized (4 pixels/thread).
// Component access only via comp4/setcomp4 with unrolled-constant j
// (rule #20: everything stays in registers, no scratch).
__global__ __launch_bounds__(256) void k_final(
    const float* __restrict__ y, const float* __restrict__ v,
    const float* __restrict__ gds, const float* __restrict__ cadc,
    const float* __restrict__ myoc, const float* __restrict__ ws,
    const double* __restrict__ acc, float* __restrict__ out) {
  const size_t p = ((size_t)blockIdx.x * blockDim.x + threadIdx.x) * 4;
  if (p >= NHW) return;

  const float m0 = (float)(acc[0] / (double)NHW);
  const float cad0 = fmaxf(cadc[0], 0.f);
  const float cad1 = fmaxf(cadc[1], 0.f);
  const float cad2 = fmaxf(cadc[2], 0.f);
  const float my0 = fmaxf(myoc[0], 0.f);
  const float my1 = fmaxf(myoc[1], 0.f);
  const float my2 = fmaxf(myoc[2], 0.f);
  const float my3 = fmaxf(myoc[3], 0.f);
  const float my4 = fmaxf(myoc[4], 0.f);

  const float4 M00 = *(const float4*)(y + p);
  const float4 M01 = *(const float4*)(y + p + (size_t)NHW);
  const float4 M10 = *(const float4*)(y + p + 2 * (size_t)NHW);
  const float4 M11 = *(const float4*)(y + p + 3 * (size_t)NHW);
  const float4 CC = *(const float4*)(y + p + 4 * (size_t)NHW);
  const float4 V0 = *(const float4*)(v + p);
  const float4 V1 = *(const float4*)(v + p + (size_t)NHW);
  const float4 GG = *(const float4*)(gds + p);

  const float4 YM00 = *(const float4*)(ws + p);
  const float4 YM01 = *(const float4*)(ws + p + (size_t)NHW);
  const float4 YM10 = *(const float4*)(ws + p + 2 * (size_t)NHW);
  const float4 YM11 = *(const float4*)(ws + p + 3 * (size_t)NHW);
  const float4 YC = *(const float4*)(ws + p + 4 * (size_t)NHW);
  const float4 YV0 = *(const float4*)(ws + p + 5 * (size_t)NHW);
  const float4 YV1 = *(const float4*)(ws + p + 6 * (size_t)NHW);
  const float4 XM00 = *(const float4*)(ws + p + 7 * (size_t)NHW);
  const float4 XM01 = *(const float4*)(ws + p + 8 * (size_t)NHW);
  const float4 XM10 = *(const float4*)(ws + p + 9 * (size_t)NHW);
  const float4 XM11 = *(const float4*)(ws + p + 10 * (size_t)NHW);
  const float4 XC = *(const float4*)(ws + p + 11 * (size_t)NHW);
  const float4 XV0 = *(const float4*)(ws + p + 12 * (size_t)NHW);
  const float4 XV1 = *(const float4*)(ws + p + 13 * (size_t)NHW);

  float4 O0, O1, O2, O3, O4;

#pragma unroll
  for (int j = 0; j < 4; ++j) {
    const float m00 = comp4(M00, j), m01 = comp4(M01, j);
    const float m10 = comp4(M10, j), m11 = comp4(M11, j);
    const float c = comp4(CC, j);
    const float v0 = comp4(V0, j), v1 = comp4(V1, j);
    const float g = comp4(GG, j);
    const float dY_m00 = comp4(YM00, j), dY_m01 = comp4(YM01, j);
    const float dY_m10 = comp4(YM10, j), dY_m11 = comp4(YM11, j);
    const float dY_c = comp4(YC, j);
    const float dY_v0 = comp4(YV0, j), dY_v1 = comp4(YV1, j);
    const float dX_m00 = comp4(XM00, j), dX_m01 = comp4(XM01, j);
    const float dX_m10 = comp4(XM10, j), dX_m11 = comp4(XM11, j);
    const float dX_c = comp4(XC, j);
    const float dX_v0 = comp4(XV0, j), dX_v1 = comp4(XV1, j);

    // gv[i][j] = d_j v_i ; j=0 -> Y, j=1 -> X
    const float gv00 = dY_v0, gv01 = dX_v0, gv10 = dY_v1, gv11 = dX_v1;
    const float ww = -0.5f * (gv01 - gv10);
    const float E00 = gv00, E11 = gv11;
    const float E01 = 0.5f * (gv01 + gv10);
    const float E10 = E01;

    const float trm = m00 + m11;
    const float dev00 = m00 - 0.5f * trm;
    const float dev01 = m01;
    const float dev10 = m10;
    const float dev11 = m11 - 0.5f * trm;
    const float dmag_sq =
        dev00 * dev00 + dev01 * dev01 + dev10 * dev10 + dev11 * dev11;
    const float dm = sqrtf(dmag_sq);
    const float dm2 = dm * dm;  // reference squares the sqrt
    const float devE = dev00 * E00 + dev01 * E01 + dev10 * E10 + dev11 * E11;
    const float sg = (devE > 0.f) ? 1.f : ((devE < 0.f) ? -1.f : 0.f);
    const float coef = sg * devE / dm2;
    const float sc = 0.5f * dm / m0;

    const float Ea00 = (E00 - coef * dev00) * sc;
    const float Ea01 = (E01 - coef * dev01) * sc;
    const float Ea10 = (E10 - coef * dev10) * sc;
    const float Ea11 = (E11 - coef * dev11) * sc;
    const float Ep00 = E00 - Ea00;
    const float Ep01 = E01 - Ea01;
    const float Ep10 = E10 - Ea10;
    const float Ep11 = E11 - Ea11;

    // mE = m*Ep + Ep*m
    const float mE00 = (m00 * Ep00 + m01 * Ep10) + (Ep00 * m00 + Ep01 * m10);
    const float mE01 = (m00 * Ep01 + m01 * Ep11) + (Ep00 * m01 + Ep01 * m11);
    const float mE10 = (m10 * Ep00 + m11 * Ep10) + (Ep10 * m00 + Ep11 * m10);
    const float mE11 = (m10 * Ep01 + m11 * Ep11) + (Ep10 * m01 + Ep11 * m11);

    const float divv = gv00 + gv11;
    const float cdot =
        -(v0 * dY_c + v1 * dX_c) - cad0 * c + cad1 * c * divv + cad2 * g;

    const float md00 = -(v0 * dY_m00 + v1 * dX_m00) - ww * m10 - ww * m01 -
                       my0 * m00 + my1 * mE00 - my2 * c * mE00 + my3 * trm +
                       my4 * trm * m00;
    const float md01 = -(v0 * dY_m01 + v1 * dX_m01) - ww * m11 + ww * m00 -
                       my0 * m01 + my1 * mE01 - my2 * c * mE01 +
                       my4 * trm * m01;
    const float md10 = -(v0 * dY_m10 + v1 * dX_m10) + ww * m00 - ww * m11 -
                       my0 * m10 + my1 * mE10 - my2 * c * mE10 +
                       my4 * trm * m10;
    const float md11 = -(v0 * dY_m11 + v1 * dX_m11) + ww * m01 + ww * m10 -
                       my0 * m11 + my1 * mE11 - my2 * c * mE11 +
                       my4 * trm * m11;

    setcomp4(O0, j, md00);
    setcomp4(O1, j, md01);
    setcomp4(O2, j, md10);
    setcomp4(O3, j, md11);
    setcomp4(O4, j, cdot);
  }

  *(float4*)(out + p) = O0;
  *(float4*)(out + p + (size_t)NHW) = O1;
  *(float4*)(out + p + 2 * (size_t)NHW) = O2;
  *(float4*)(out + p + 3 * (size_t)NHW) = O3;
  *(float4*)(out + p + 4 * (size_t)NHW) = O4;
}

extern "C" void kernel_launch(void* const* d_in, const int* in_sizes, int n_in,
                              void* d_out, int out_size, void* d_ws, size_t ws_size,
                              hipStream_t stream) {
  (void)in_sizes; (void)n_in; (void)out_size; (void)ws_size;
  const float* y = (const float*)d_in[0];
  const float* v = (const float*)d_in[1];
  const float* gds = (const float*)d_in[2];
  const float* cadc = (const float*)d_in[3];
  const float* myoc = (const float*)d_in[4];
  float* out = (float*)d_out;

  double* acc = (double*)d_ws;                       // 8B accumulator
  float* planes = (float*)((char*)d_ws + 512);       // 14 x NHW fp32 planes

  hipMemsetAsync(acc, 0, sizeof(double), stream);
  k_reduce<<<dim3(1024), dim3(256), 0, stream>>>(y, acc);
  k_dx<<<dim3(NH, 7), dim3(256), 0, stream>>>(y, v, planes);
  k_dy<<<dim3(NW / TW, NH / TH, 7), dim3(256), 0, stream>>>(y, v, planes);
  k_final<<<dim3(NHW / 1024), dim3(256), 0, stream>>>(y, v, gds, cadc, myoc, planes, acc, out);
}

// Round 5
// 179.731 us; speedup vs baseline: 1.2672x; 1.0930x over previous
//
#include <hip/hip_runtime.h>
#include <math.h>

#define RAD 20
#define KLEN 41
#define NH 1024
#define NW 2048
#define NHW (NH * NW)

// ---- Compile-time Gaussian-derivative weights (fp64, matches numpy) ----
struct KW { float w[KLEN]; };
constexpr double cexp_neg(double u) {  // exp(-u), 0 <= u <= 0.5
  double term = 1.0, sum = 1.0;
  for (int k = 1; k < 30; ++k) { term *= (-u) / (double)k; sum += term; }
  return sum;
}
constexpr KW make_kw() {
  KW r{};
  double ph[KLEN] = {};
  double s = 0.0;
  for (int i = 0; i < KLEN; ++i) {
    double d = (double)(i - RAD);
    double e = cexp_neg(d * d / 800.0);
    e = e * e; e = e * e; e = e * e; e = e * e;  // ^16
    ph[i] = e; s += e;
  }
  for (int i = 0; i < KLEN; ++i) {
    double d = (double)(i - RAD);
    r.w[i] = (float)((-d / 25.0) * (ph[i] / s) / 2.27);
  }
  return r;
}
static constexpr KW KWC = make_kw();

// Tap-major conv core, 8-accumulator form.
template <int K>
__device__ __forceinline__ void tap(float s, float& r0, float& r1, float& r2,
                                    float& r3, float& r4, float& r5, float& r6,
                                    float& r7) {
  if constexpr (K - 0 >= 0 && K - 0 <= 40) r0 = fmaf(s, KWC.w[K - 0], r0);
  if constexpr (K - 1 >= 0 && K - 1 <= 40) r1 = fmaf(s, KWC.w[K - 1], r1);
  if constexpr (K - 2 >= 0 && K - 2 <= 40) r2 = fmaf(s, KWC.w[K - 2], r2);
  if constexpr (K - 3 >= 0 && K - 3 <= 40) r3 = fmaf(s, KWC.w[K - 3], r3);
  if constexpr (K - 4 >= 0 && K - 4 <= 40) r4 = fmaf(s, KWC.w[K - 4], r4);
  if constexpr (K - 5 >= 0 && K - 5 <= 40) r5 = fmaf(s, KWC.w[K - 5], r5);
  if constexpr (K - 6 >= 0 && K - 6 <= 40) r6 = fmaf(s, KWC.w[K - 6], r6);
  if constexpr (K - 7 >= 0 && K - 7 <= 40) r7 = fmaf(s, KWC.w[K - 7], r7);
}

#define R8 r0, r1, r2, r3, r4, r5, r6, r7

#define TW 64  // tile width (x)
#define TH 32  // output rows per block
#define TILE_CH ((TH + 2 * RAD) * TW)  // 72*64 = 4608 floats per channel slot

// Column conv along y within a staged channel tile (same chunk/tap order as
// the original k_dy -> bit-identical dY results).
__device__ __forceinline__ void conv_col(const float* __restrict__ t, int base,
                                         int lane, float& r0, float& r1,
                                         float& r2, float& r3, float& r4,
                                         float& r5, float& r6, float& r7) {
#define CCHUNK(c)                                      \
  {                                                    \
    float s0 = t[(base + 4 * (c) + 0) * TW + lane];    \
    float s1 = t[(base + 4 * (c) + 1) * TW + lane];    \
    float s2 = t[(base + 4 * (c) + 2) * TW + lane];    \
    float s3 = t[(base + 4 * (c) + 3) * TW + lane];    \
    tap<4 * (c) + 0>(s0, R8);                          \
    tap<4 * (c) + 1>(s1, R8);                          \
    tap<4 * (c) + 2>(s2, R8);                          \
    tap<4 * (c) + 3>(s3, R8);                          \
  }
  CCHUNK(0) CCHUNK(1) CCHUNK(2) CCHUNK(3) CCHUNK(4) CCHUNK(5)
  CCHUNK(6) CCHUNK(7) CCHUNK(8) CCHUNK(9) CCHUNK(10) CCHUNK(11)
#undef CCHUNK
}

// m_0 numerator: sum over pixels of ||m||_F (fp32 sqrt, fp64 accumulate).
__global__ __launch_bounds__(256) void k_reduce(const float* __restrict__ y,
                                                double* __restrict__ acc) {
  const int tid = blockIdx.x * blockDim.x + threadIdx.x;
  const int stride = gridDim.x * blockDim.x;
  double local = 0.0;
  for (int q = tid; q < NHW / 4; q += stride) {
    float4 a = ((const float4*)y)[q];
    float4 b = ((const float4*)(y + NHW))[q];
    float4 c = ((const float4*)(y + 2 * (size_t)NHW))[q];
    float4 d = ((const float4*)(y + 3 * (size_t)NHW))[q];
    local += (double)sqrtf(a.x * a.x + b.x * b.x + c.x * c.x + d.x * d.x);
    local += (double)sqrtf(a.y * a.y + b.y * b.y + c.y * c.y + d.y * d.y);
    local += (double)sqrtf(a.z * a.z + b.z * b.z + c.z * c.z + d.z * d.z);
    local += (double)sqrtf(a.w * a.w + b.w * b.w + c.w * c.w + d.w * d.w);
  }
#pragma unroll
  for (int off = 32; off > 0; off >>= 1) local += __shfl_down(local, off, 64);
  __shared__ double smem[4];
  const int lane = threadIdx.x & 63;
  const int wid = threadIdx.x >> 6;
  if (lane == 0) smem[wid] = local;
  __syncthreads();
  if (threadIdx.x == 0) {
    double s = smem[0] + smem[1] + smem[2] + smem[3];
    atomicAdd(acc, s);
  }
}

// diffX with swizzled-LDS scalar reads (round-8 pattern: addr(x)=x+(x>>6),
// <=2-way banks on every read/write). Writes ws planes 7..13.
__global__ __launch_bounds__(256) void k_dx(const float* __restrict__ y,
                                            const float* __restrict__ v,
                                            float* __restrict__ ws) {
  __shared__ float row[2120];  // 2088 padded floats, swizzle-expanded
  const int t = threadIdx.x;
  const int r = blockIdx.x;
  const int ch = blockIdx.y;  // 0..6 -> y0..y4, v0, v1
  const float* src = (ch < 5) ? (y + (size_t)ch * NHW) : (v + (size_t)(ch - 5) * NHW);
  const float* rp = src + (size_t)r * NW;

#define SWZ(i) ((i) + ((i) >> 6))
#define ST(i, val) { const int ii_ = (i); row[SWZ(ii_)] = (val); }

  const float4* rp4 = (const float4*)rp;
  float4 b0 = rp4[t];
  float4 b1 = rp4[t + 256];
  ST(RAD + 4 * t + 0, b0.x)
  ST(RAD + 4 * t + 1, b0.y)
  ST(RAD + 4 * t + 2, b0.z)
  ST(RAD + 4 * t + 3, b0.w)
  ST(RAD + 4 * (t + 256) + 0, b1.x)
  ST(RAD + 4 * (t + 256) + 1, b1.y)
  ST(RAD + 4 * (t + 256) + 2, b1.z)
  ST(RAD + 4 * (t + 256) + 3, b1.w)
  if (t < RAD) {
    ST(t, rp[RAD - t])                // left reflect (no edge repeat)
    ST(NW + RAD + t, rp[NW - 2 - t])  // right reflect
  }
  __syncthreads();

  const int xb = 8 * t;
  float r0 = 0.f, r1 = 0.f, r2 = 0.f, r3 = 0.f;
  float r4 = 0.f, r5 = 0.f, r6 = 0.f, r7 = 0.f;
#define RD(k) { const int x_ = xb + (k); float s_ = row[SWZ(x_)]; tap<(k)>(s_, R8); }
  RD(0)  RD(1)  RD(2)  RD(3)  RD(4)  RD(5)  RD(6)  RD(7)
  RD(8)  RD(9)  RD(10) RD(11) RD(12) RD(13) RD(14) RD(15)
  RD(16) RD(17) RD(18) RD(19) RD(20) RD(21) RD(22) RD(23)
  RD(24) RD(25) RD(26) RD(27) RD(28) RD(29) RD(30) RD(31)
  RD(32) RD(33) RD(34) RD(35) RD(36) RD(37) RD(38) RD(39)
  RD(40) RD(41) RD(42) RD(43) RD(44) RD(45) RD(46) RD(47)
#undef RD

  float4 o0, o1;
  o0.x = r0; o0.y = r1; o0.z = r2; o0.w = r3;
  o1.x = r4; o1.y = r5; o1.z = r6; o1.w = r7;
  float4* dst = (float4*)(ws + (size_t)(7 + ch) * NHW + (size_t)r * NW + xb);
  dst[0] = o0;
  dst[1] = o1;
}

// ---- Fused diffY + pointwise tensor algebra ----
// Stages channels in two groups (m00..m11 then c,v0,v1; max 73.7 KB LDS ->
// 2 blocks/CU), holds all 7 dY results (56 regs/thread), then applies the
// 2x2 algebra and writes out directly. Eliminates the 7-plane dY round trip
// (~117 MB HBM). c/v0/v1 pointwise inputs come from LDS group B (still
// resident); m-planes re-read from global (L2-warm from staging).
__global__ __launch_bounds__(256) void k_dyf(
    const float* __restrict__ y, const float* __restrict__ v,
    const float* __restrict__ gds, const float* __restrict__ cadc,
    const float* __restrict__ myoc, const float* __restrict__ ws,
    const double* __restrict__ acc, float* __restrict__ out) {
  __shared__ float tile[4 * TILE_CH];  // 73728 B
  const int lane = threadIdx.x & 63;
  const int wid = threadIdx.x >> 6;  // 0..3
  const int x0 = blockIdx.x * TW;
  const int yb = blockIdx.y * TH;
  const int base = wid * 8;

  const float m0 = (float)(acc[0] / (double)NHW);
  const float cad0 = fmaxf(cadc[0], 0.f);
  const float cad1 = fmaxf(cadc[1], 0.f);
  const float cad2 = fmaxf(cadc[2], 0.f);
  const float my0 = fmaxf(myoc[0], 0.f);
  const float my1 = fmaxf(myoc[1], 0.f);
  const float my2 = fmaxf(myoc[2], 0.f);
  const float my3 = fmaxf(myoc[3], 0.f);
  const float my4 = fmaxf(myoc[4], 0.f);

// Stage one channel tile (72 rows x 64 cols, wrap in y): 18 coalesced loads
// into named regs, then 18 LDS writes. Wave w stages rows w, w+4, ..., w+68.
#define SGLD(sp, k) \
  (sp)[(size_t)(((yb - RAD + wid + 4 * (k)) + NH) & (NH - 1)) * NW + x0 + lane]
#define STAGECH(g, srcp)                                                    \
  {                                                                         \
    const float* sp_ = (srcp);                                              \
    float u0 = SGLD(sp_, 0), u1 = SGLD(sp_, 1), u2 = SGLD(sp_, 2);          \
    float u3 = SGLD(sp_, 3), u4 = SGLD(sp_, 4), u5 = SGLD(sp_, 5);          \
    float u6 = SGLD(sp_, 6), u7 = SGLD(sp_, 7), u8 = SGLD(sp_, 8);          \
    float u9 = SGLD(sp_, 9), u10 = SGLD(sp_, 10), u11 = SGLD(sp_, 11);      \
    float u12 = SGLD(sp_, 12), u13 = SGLD(sp_, 13), u14 = SGLD(sp_, 14);    \
    float u15 = SGLD(sp_, 15), u16 = SGLD(sp_, 16), u17 = SGLD(sp_, 17);    \
    float* tb_ = &tile[(g) * TILE_CH];                                      \
    tb_[(wid + 0) * TW + lane] = u0;   tb_[(wid + 4) * TW + lane] = u1;     \
    tb_[(wid + 8) * TW + lane] = u2;   tb_[(wid + 12) * TW + lane] = u3;    \
    tb_[(wid + 16) * TW + lane] = u4;  tb_[(wid + 20) * TW + lane] = u5;    \
    tb_[(wid + 24) * TW + lane] = u6;  tb_[(wid + 28) * TW + lane] = u7;    \
    tb_[(wid + 32) * TW + lane] = u8;  tb_[(wid + 36) * TW + lane] = u9;    \
    tb_[(wid + 40) * TW + lane] = u10; tb_[(wid + 44) * TW + lane] = u11;   \
    tb_[(wid + 48) * TW + lane] = u12; tb_[(wid + 52) * TW + lane] = u13;   \
    tb_[(wid + 56) * TW + lane] = u14; tb_[(wid + 60) * TW + lane] = u15;   \
    tb_[(wid + 64) * TW + lane] = u16; tb_[(wid + 68) * TW + lane] = u17;   \
  }

#define DECL8(P)                                                       \
  float P##0 = 0.f, P##1 = 0.f, P##2 = 0.f, P##3 = 0.f, P##4 = 0.f,    \
        P##5 = 0.f, P##6 = 0.f, P##7 = 0.f;
#define CALLCONV(g, P)                                                  \
  conv_col(&tile[(g) * TILE_CH], base, lane, P##0, P##1, P##2, P##3,    \
           P##4, P##5, P##6, P##7);

  // Phase A: dY of m00..m11
  STAGECH(0, y)
  STAGECH(1, y + (size_t)NHW)
  STAGECH(2, y + 2 * (size_t)NHW)
  STAGECH(3, y + 3 * (size_t)NHW)
  __syncthreads();
  DECL8(ym00) DECL8(ym01) DECL8(ym10) DECL8(ym11)
  CALLCONV(0, ym00)
  CALLCONV(1, ym01)
  CALLCONV(2, ym10)
  CALLCONV(3, ym11)
  __syncthreads();  // all waves done reading group A before overwrite

  // Phase B: dY of c, v0, v1 (slots 0..2; these stay resident for phase C)
  STAGECH(0, y + 4 * (size_t)NHW)
  STAGECH(1, v)
  STAGECH(2, v + (size_t)NHW)
  __syncthreads();
  DECL8(yc) DECL8(yv0) DECL8(yv1)
  CALLCONV(0, yc)
  CALLCONV(1, yv0)
  CALLCONV(2, yv1)

  // Phase C: pointwise algebra per owned pixel (rows yb+base+q, col x0+lane).
#define POINT(q)                                                              \
  {                                                                           \
    const size_t idx = (size_t)(yb + base + (q)) * NW + x0 + lane;            \
    const int trow = (RAD + base + (q)) * TW + lane;                          \
    const float m00 = y[idx];                                                 \
    const float m01 = y[idx + (size_t)NHW];                                   \
    const float m10 = y[idx + 2 * (size_t)NHW];                               \
    const float m11 = y[idx + 3 * (size_t)NHW];                               \
    const float c = tile[0 * TILE_CH + trow];                                 \
    const float v0 = tile[1 * TILE_CH + trow];                                \
    const float v1 = tile[2 * TILE_CH + trow];                                \
    const float g = gds[idx];                                                 \
    const float dY_m00 = ym00##q, dY_m01 = ym01##q;                           \
    const float dY_m10 = ym10##q, dY_m11 = ym11##q;                           \
    const float dY_c = yc##q, dY_v0 = yv0##q, dY_v1 = yv1##q;                 \
    const float dX_m00 = ws[idx + 7 * (size_t)NHW];                           \
    const float dX_m01 = ws[idx + 8 * (size_t)NHW];                           \
    const float dX_m10 = ws[idx + 9 * (size_t)NHW];                           \
    const float dX_m11 = ws[idx + 10 * (size_t)NHW];                          \
    const float dX_c = ws[idx + 11 * (size_t)NHW];                            \
    const float dX_v0 = ws[idx + 12 * (size_t)NHW];                           \
    const float dX_v1 = ws[idx + 13 * (size_t)NHW];                           \
    const float gv00 = dY_v0, gv01 = dX_v0, gv10 = dY_v1, gv11 = dX_v1;       \
    const float ww = -0.5f * (gv01 - gv10);                                   \
    const float E00 = gv00, E11 = gv11;                                       \
    const float E01 = 0.5f * (gv01 + gv10);                                   \
    const float E10 = E01;                                                    \
    const float trm = m00 + m11;                                              \
    const float dev00 = m00 - 0.5f * trm;                                     \
    const float dev01 = m01;                                                  \
    const float dev10 = m10;                                                  \
    const float dev11 = m11 - 0.5f * trm;                                     \
    const float dmag_sq =                                                     \
        dev00 * dev00 + dev01 * dev01 + dev10 * dev10 + dev11 * dev11;        \
    const float dm = sqrtf(dmag_sq);                                          \
    const float dm2 = dm * dm;                                                \
    const float devE = dev00 * E00 + dev01 * E01 + dev10 * E10 + dev11 * E11; \
    const float sg = (devE > 0.f) ? 1.f : ((devE < 0.f) ? -1.f : 0.f);        \
    const float coef = sg * devE / dm2;                                       \
    const float sc = 0.5f * dm / m0;                                          \
    const float Ea00 = (E00 - coef * dev00) * sc;                             \
    const float Ea01 = (E01 - coef * dev01) * sc;                             \
    const float Ea10 = (E10 - coef * dev10) * sc;                             \
    const float Ea11 = (E11 - coef * dev11) * sc;                             \
    const float Ep00 = E00 - Ea00;                                            \
    const float Ep01 = E01 - Ea01;                                            \
    const float Ep10 = E10 - Ea10;                                            \
    const float Ep11 = E11 - Ea11;                                            \
    const float mE00 = (m00 * Ep00 + m01 * Ep10) + (Ep00 * m00 + Ep01 * m10); \
    const float mE01 = (m00 * Ep01 + m01 * Ep11) + (Ep00 * m01 + Ep01 * m11); \
    const float mE10 = (m10 * Ep00 + m11 * Ep10) + (Ep10 * m00 + Ep11 * m10); \
    const float mE11 = (m10 * Ep01 + m11 * Ep11) + (Ep10 * m01 + Ep11 * m11); \
    const float divv = gv00 + gv11;                                           \
    const float cdot =                                                        \
        -(v0 * dY_c + v1 * dX_c) - cad0 * c + cad1 * c * divv + cad2 * g;     \
    const float md00 = -(v0 * dY_m00 + v1 * dX_m00) - ww * m10 - ww * m01 -   \
                       my0 * m00 + my1 * mE00 - my2 * c * mE00 + my3 * trm +  \
                       my4 * trm * m00;                                       \
    const float md01 = -(v0 * dY_m01 + v1 * dX_m01) - ww * m11 + ww * m00 -   \
                       my0 * m01 + my1 * mE01 - my2 * c * mE01 +              \
                       my4 * trm * m01;                                       \
    const float md10 = -(v0 * dY_m10 + v1 * dX_m10) + ww * m00 - ww * m11 -   \
                       my0 * m10 + my1 * mE10 - my2 * c * mE10 +              \
                       my4 * trm * m10;                                       \
    const float md11 = -(v0 * dY_m11 + v1 * dX_m11) + ww * m01 + ww * m10 -   \
                       my0 * m11 + my1 * mE11 - my2 * c * mE11 +              \
                       my4 * trm * m11;                                       \
    out[idx] = md00;                                                          \
    out[idx + (size_t)NHW] = md01;                                            \
    out[idx + 2 * (size_t)NHW] = md10;                                        \
    out[idx + 3 * (size_t)NHW] = md11;                                        \
    out[idx + 4 * (size_t)NHW] = cdot;                                        \
  }

  POINT(0) POINT(1) POINT(2) POINT(3)
  POINT(4) POINT(5) POINT(6) POINT(7)
#undef POINT
}

extern "C" void kernel_launch(void* const* d_in, const int* in_sizes, int n_in,
                              void* d_out, int out_size, void* d_ws, size_t ws_size,
                              hipStream_t stream) {
  (void)in_sizes; (void)n_in; (void)out_size; (void)ws_size;
  const float* y = (const float*)d_in[0];
  const float* v = (const float*)d_in[1];
  const float* gds = (const float*)d_in[2];
  const float* cadc = (const float*)d_in[3];
  const float* myoc = (const float*)d_in[4];
  float* out = (float*)d_out;

  double* acc = (double*)d_ws;                       // 8B accumulator
  float* planes = (float*)((char*)d_ws + 512);       // 14 x NHW fp32 planes (7..13 used)

  hipMemsetAsync(acc, 0, sizeof(double), stream);
  k_reduce<<<dim3(1024), dim3(256), 0, stream>>>(y, acc);
  k_dx<<<dim3(NH, 7), dim3(256), 0, stream>>>(y, v, planes);
  k_dyf<<<dim3(NW / TW, NH / TH), dim3(256), 0, stream>>>(y, v, gds, cadc, myoc,
                                                          planes, acc, out);
}

// Round 7
// 179.566 us; speedup vs baseline: 1.2684x; 1.0009x over previous
//
#include <hip/hip_runtime.h>
#include <math.h>

#define RAD 20
#define KLEN 41
#define NH 1024
#define NW 2048
#define NHW (NH * NW)

// ---- Compile-time Gaussian-derivative weights (fp64, matches numpy) ----
struct KW { float w[KLEN]; };
constexpr double cexp_neg(double u) {  // exp(-u), 0 <= u <= 0.5
  double term = 1.0, sum = 1.0;
  for (int k = 1; k < 30; ++k) { term *= (-u) / (double)k; sum += term; }
  return sum;
}
constexpr KW make_kw() {
  KW r{};
  double ph[KLEN] = {};
  double s = 0.0;
  for (int i = 0; i < KLEN; ++i) {
    double d = (double)(i - RAD);
    double e = cexp_neg(d * d / 800.0);
    e = e * e; e = e * e; e = e * e; e = e * e;  // ^16
    ph[i] = e; s += e;
  }
  for (int i = 0; i < KLEN; ++i) {
    double d = (double)(i - RAD);
    r.w[i] = (float)((-d / 25.0) * (ph[i] / s) / 2.27);
  }
  return r;
}
static constexpr KW KWC = make_kw();

// Tap-major conv core, 8-accumulator form.
template <int K>
__device__ __forceinline__ void tap(float s, float& r0, float& r1, float& r2,
                                    float& r3, float& r4, float& r5, float& r6,
                                    float& r7) {
  if constexpr (K - 0 >= 0 && K - 0 <= 40) r0 = fmaf(s, KWC.w[K - 0], r0);
  if constexpr (K - 1 >= 0 && K - 1 <= 40) r1 = fmaf(s, KWC.w[K - 1], r1);
  if constexpr (K - 2 >= 0 && K - 2 <= 40) r2 = fmaf(s, KWC.w[K - 2], r2);
  if constexpr (K - 3 >= 0 && K - 3 <= 40) r3 = fmaf(s, KWC.w[K - 3], r3);
  if constexpr (K - 4 >= 0 && K - 4 <= 40) r4 = fmaf(s, KWC.w[K - 4], r4);
  if constexpr (K - 5 >= 0 && K - 5 <= 40) r5 = fmaf(s, KWC.w[K - 5], r5);
  if constexpr (K - 6 >= 0 && K - 6 <= 40) r6 = fmaf(s, KWC.w[K - 6], r6);
  if constexpr (K - 7 >= 0 && K - 7 <= 40) r7 = fmaf(s, KWC.w[K - 7], r7);
}

#define R8 r0, r1, r2, r3, r4, r5, r6, r7

#define TW 64  // tile width (x)
#define TH 32  // output rows per block
#define TILE_CH ((TH + 2 * RAD) * TW)  // 72*64 = 4608 floats per channel slot

// Column conv along y within a staged channel tile (same chunk/tap order as
// the original k_dy -> bit-identical dY results).
__device__ __forceinline__ void conv_col(const float* __restrict__ t, int base,
                                         int lane, float& r0, float& r1,
                                         float& r2, float& r3, float& r4,
                                         float& r5, float& r6, float& r7) {
#define CCHUNK(c)                                      \
  {                                                    \
    float s0 = t[(base + 4 * (c) + 0) * TW + lane];    \
    float s1 = t[(base + 4 * (c) + 1) * TW + lane];    \
    float s2 = t[(base + 4 * (c) + 2) * TW + lane];    \
    float s3 = t[(base + 4 * (c) + 3) * TW + lane];    \
    tap<4 * (c) + 0>(s0, R8);                          \
    tap<4 * (c) + 1>(s1, R8);                          \
    tap<4 * (c) + 2>(s2, R8);                          \
    tap<4 * (c) + 3>(s3, R8);                          \
  }
  CCHUNK(0) CCHUNK(1) CCHUNK(2) CCHUNK(3) CCHUNK(4) CCHUNK(5)
  CCHUNK(6) CCHUNK(7) CCHUNK(8) CCHUNK(9) CCHUNK(10) CCHUNK(11)
#undef CCHUNK
}

// m_0 numerator: sum over pixels of ||m||_F (fp32 sqrt, fp64 accumulate).
__global__ __launch_bounds__(256) void k_reduce(const float* __restrict__ y,
                                                double* __restrict__ acc) {
  const int tid = blockIdx.x * blockDim.x + threadIdx.x;
  const int stride = gridDim.x * blockDim.x;
  double local = 0.0;
  for (int q = tid; q < NHW / 4; q += stride) {
    float4 a = ((const float4*)y)[q];
    float4 b = ((const float4*)(y + NHW))[q];
    float4 c = ((const float4*)(y + 2 * (size_t)NHW))[q];
    float4 d = ((const float4*)(y + 3 * (size_t)NHW))[q];
    local += (double)sqrtf(a.x * a.x + b.x * b.x + c.x * c.x + d.x * d.x);
    local += (double)sqrtf(a.y * a.y + b.y * b.y + c.y * c.y + d.y * d.y);
    local += (double)sqrtf(a.z * a.z + b.z * b.z + c.z * c.z + d.z * d.z);
    local += (double)sqrtf(a.w * a.w + b.w * b.w + c.w * c.w + d.w * d.w);
  }
#pragma unroll
  for (int off = 32; off > 0; off >>= 1) local += __shfl_down(local, off, 64);
  __shared__ double smem[4];
  const int lane = threadIdx.x & 63;
  const int wid = threadIdx.x >> 6;
  if (lane == 0) smem[wid] = local;
  __syncthreads();
  if (threadIdx.x == 0) {
    double s = smem[0] + smem[1] + smem[2] + smem[3];
    atomicAdd(acc, s);
  }
}

// diffX with swizzled-LDS scalar reads (round-8 pattern: addr(x)=x+(x>>6),
// <=2-way banks on every read/write). Writes ws planes 7..13.
__global__ __launch_bounds__(256) void k_dx(const float* __restrict__ y,
                                            const float* __restrict__ v,
                                            float* __restrict__ ws) {
  __shared__ float row[2120];  // 2088 padded floats, swizzle-expanded
  const int t = threadIdx.x;
  const int r = blockIdx.x;
  const int ch = blockIdx.y;  // 0..6 -> y0..y4, v0, v1
  const float* src = (ch < 5) ? (y + (size_t)ch * NHW) : (v + (size_t)(ch - 5) * NHW);
  const float* rp = src + (size_t)r * NW;

#define SWZ(i) ((i) + ((i) >> 6))
#define ST(i, val) { const int ii_ = (i); row[SWZ(ii_)] = (val); }

  const float4* rp4 = (const float4*)rp;
  float4 b0 = rp4[t];
  float4 b1 = rp4[t + 256];
  ST(RAD + 4 * t + 0, b0.x)
  ST(RAD + 4 * t + 1, b0.y)
  ST(RAD + 4 * t + 2, b0.z)
  ST(RAD + 4 * t + 3, b0.w)
  ST(RAD + 4 * (t + 256) + 0, b1.x)
  ST(RAD + 4 * (t + 256) + 1, b1.y)
  ST(RAD + 4 * (t + 256) + 2, b1.z)
  ST(RAD + 4 * (t + 256) + 3, b1.w)
  if (t < RAD) {
    ST(t, rp[RAD - t])                // left reflect (no edge repeat)
    ST(NW + RAD + t, rp[NW - 2 - t])  // right reflect
  }
  __syncthreads();

  const int xb = 8 * t;
  float r0 = 0.f, r1 = 0.f, r2 = 0.f, r3 = 0.f;
  float r4 = 0.f, r5 = 0.f, r6 = 0.f, r7 = 0.f;
#define RD(k) { const int x_ = xb + (k); float s_ = row[SWZ(x_)]; tap<(k)>(s_, R8); }
  RD(0)  RD(1)  RD(2)  RD(3)  RD(4)  RD(5)  RD(6)  RD(7)
  RD(8)  RD(9)  RD(10) RD(11) RD(12) RD(13) RD(14) RD(15)
  RD(16) RD(17) RD(18) RD(19) RD(20) RD(21) RD(22) RD(23)
  RD(24) RD(25) RD(26) RD(27) RD(28) RD(29) RD(30) RD(31)
  RD(32) RD(33) RD(34) RD(35) RD(36) RD(37) RD(38) RD(39)
  RD(40) RD(41) RD(42) RD(43) RD(44) RD(45) RD(46) RD(47)
#undef RD

  float4 o0, o1;
  o0.x = r0; o0.y = r1; o0.z = r2; o0.w = r3;
  o1.x = r4; o1.y = r5; o1.z = r6; o1.w = r7;
  float4* dst = (float4*)(ws + (size_t)(7 + ch) * NHW + (size_t)r * NW + xb);
  dst[0] = o0;
  dst[1] = o1;
}

// ---- Fused diffY + pointwise, 2-slot software-pipelined staging ----
// 2 slots (36.9KB -> 4 blocks/CU), channels staged one at a time through
// alternating slots; ch(i+1)'s global loads issue BEFORE ch i's conv so HBM
// latency hides under ~800 FMAs (T14). One barrier per channel. In step i
// all waves conv-read slot i&1 and write slot (i+1)&1; the written slot was
// last read in step i-1, sealed by step i-1's barrier -> race-free.
// Phase C reads m/c/v from global (L2-hot). Conv chunk/tap order identical
// to the original k_dy -> bit-identical dY.
__global__ __launch_bounds__(256, 4) void k_dyf(
    const float* __restrict__ y, const float* __restrict__ v,
    const float* __restrict__ gds, const float* __restrict__ cadc,
    const float* __restrict__ myoc, const float* __restrict__ ws,
    const double* __restrict__ acc, float* __restrict__ out) {
  __shared__ float tile[2 * TILE_CH];  // 36864 B
  const int lane = threadIdx.x & 63;
  const int wid = threadIdx.x >> 6;  // 0..3
  const int x0 = blockIdx.x * TW;
  const int yb = blockIdx.y * TH;
  const int base = wid * 8;

  const float m0 = (float)(acc[0] / (double)NHW);
  const float cad0 = fmaxf(cadc[0], 0.f);
  const float cad1 = fmaxf(cadc[1], 0.f);
  const float cad2 = fmaxf(cadc[2], 0.f);
  const float my0 = fmaxf(myoc[0], 0.f);
  const float my1 = fmaxf(myoc[1], 0.f);
  const float my2 = fmaxf(myoc[2], 0.f);
  const float my3 = fmaxf(myoc[3], 0.f);
  const float my4 = fmaxf(myoc[4], 0.f);

#define SGLD(sp, k) \
  (sp)[(size_t)(((yb - RAD + wid + 4 * (k)) + NH) & (NH - 1)) * NW + x0 + lane]

  float u0, u1, u2, u3, u4, u5, u6, u7, u8;
  float u9, u10, u11, u12, u13, u14, u15, u16, u17;

#define LOADCH(srcp)                                                   \
  {                                                                    \
    const float* sp_ = (srcp);                                         \
    u0 = SGLD(sp_, 0); u1 = SGLD(sp_, 1); u2 = SGLD(sp_, 2);           \
    u3 = SGLD(sp_, 3); u4 = SGLD(sp_, 4); u5 = SGLD(sp_, 5);           \
    u6 = SGLD(sp_, 6); u7 = SGLD(sp_, 7); u8 = SGLD(sp_, 8);           \
    u9 = SGLD(sp_, 9); u10 = SGLD(sp_, 10); u11 = SGLD(sp_, 11);       \
    u12 = SGLD(sp_, 12); u13 = SGLD(sp_, 13); u14 = SGLD(sp_, 14);     \
    u15 = SGLD(sp_, 15); u16 = SGLD(sp_, 16); u17 = SGLD(sp_, 17);     \
  }
#define WRITECH(g)                                                        \
  {                                                                       \
    float* tb_ = &tile[(g) * TILE_CH];                                    \
    tb_[(wid + 0) * TW + lane] = u0;   tb_[(wid + 4) * TW + lane] = u1;   \
    tb_[(wid + 8) * TW + lane] = u2;   tb_[(wid + 12) * TW + lane] = u3;  \
    tb_[(wid + 16) * TW + lane] = u4;  tb_[(wid + 20) * TW + lane] = u5;  \
    tb_[(wid + 24) * TW + lane] = u6;  tb_[(wid + 28) * TW + lane] = u7;  \
    tb_[(wid + 32) * TW + lane] = u8;  tb_[(wid + 36) * TW + lane] = u9;  \
    tb_[(wid + 40) * TW + lane] = u10; tb_[(wid + 44) * TW + lane] = u11; \
    tb_[(wid + 48) * TW + lane] = u12; tb_[(wid + 52) * TW + lane] = u13; \
    tb_[(wid + 56) * TW + lane] = u14; tb_[(wid + 60) * TW + lane] = u15; \
    tb_[(wid + 64) * TW + lane] = u16; tb_[(wid + 68) * TW + lane] = u17; \
  }
#define DECL8(P)                                                       \
  float P##0 = 0.f, P##1 = 0.f, P##2 = 0.f, P##3 = 0.f, P##4 = 0.f,    \
        P##5 = 0.f, P##6 = 0.f, P##7 = 0.f;
#define CALLCONV(g, P)                                                  \
  conv_col(&tile[(g) * TILE_CH], base, lane, P##0, P##1, P##2, P##3,    \
           P##4, P##5, P##6, P##7);

  DECL8(ym00) DECL8(ym01) DECL8(ym10) DECL8(ym11)
  DECL8(yc) DECL8(yv0) DECL8(yv1)

  // Prologue: stage ch0 (m00) into slot 0.
  LOADCH(y)
  WRITECH(0)
  __syncthreads();
  // Step 0: conv m00 (slot0); prefetch+write m01 -> slot1.
  LOADCH(y + (size_t)NHW)
  CALLCONV(0, ym00)
  WRITECH(1)
  __syncthreads();
  // Step 1: conv m01 (slot1); prefetch+write m10 -> slot0.
  LOADCH(y + 2 * (size_t)NHW)
  CALLCONV(1, ym01)
  WRITECH(0)
  __syncthreads();
  // Step 2: conv m10 (slot0); prefetch+write m11 -> slot1.
  LOADCH(y + 3 * (size_t)NHW)
  CALLCONV(0, ym10)
  WRITECH(1)
  __syncthreads();
  // Step 3: conv m11 (slot1); prefetch+write c -> slot0.
  LOADCH(y + 4 * (size_t)NHW)
  CALLCONV(1, ym11)
  WRITECH(0)
  __syncthreads();
  // Step 4: conv c (slot0); prefetch+write v0 -> slot1.
  LOADCH(v)
  CALLCONV(0, yc)
  WRITECH(1)
  __syncthreads();
  // Step 5: conv v0 (slot1); prefetch+write v1 -> slot0.
  LOADCH(v + (size_t)NHW)
  CALLCONV(1, yv0)
  WRITECH(0)
  __syncthreads();
  // Step 6: conv v1 (slot0). No further staging, no barrier needed.
  CALLCONV(0, yv1)

  // Phase C: pointwise algebra per owned pixel (rows yb+base+q, col x0+lane).
  // m/c/v re-read from global: L2-hot (this block staged them just now).
#define POINT(q)                                                              \
  {                                                                           \
    const size_t idx = (size_t)(yb + base + (q)) * NW + x0 + lane;            \
    const float m00 = y[idx];                                                 \
    const float m01 = y[idx + (size_t)NHW];                                   \
    const float m10 = y[idx + 2 * (size_t)NHW];                               \
    const float m11 = y[idx + 3 * (size_t)NHW];                               \
    const float c = y[idx + 4 * (size_t)NHW];                                 \
    const float v0 = v[idx];                                                  \
    const float v1 = v[idx + (size_t)NHW];                                    \
    const float g = gds[idx];                                                 \
    const float dY_m00 = ym00##q, dY_m01 = ym01##q;                           \
    const float dY_m10 = ym10##q, dY_m11 = ym11##q;                           \
    const float dY_c = yc##q, dY_v0 = yv0##q, dY_v1 = yv1##q;                 \
    const float dX_m00 = ws[idx + 7 * (size_t)NHW];                           \
    const float dX_m01 = ws[idx + 8 * (size_t)NHW];                           \
    const float dX_m10 = ws[idx + 9 * (size_t)NHW];                           \
    const float dX_m11 = ws[idx + 10 * (size_t)NHW];                          \
    const float dX_c = ws[idx + 11 * (size_t)NHW];                            \
    const float dX_v0 = ws[idx + 12 * (size_t)NHW];                           \
    const float dX_v1 = ws[idx + 13 * (size_t)NHW];                           \
    const float gv00 = dY_v0, gv01 = dX_v0, gv10 = dY_v1, gv11 = dX_v1;       \
    const float ww = -0.5f * (gv01 - gv10);                                   \
    const float E00 = gv00, E11 = gv11;                                       \
    const float E01 = 0.5f * (gv01 + gv10);                                   \
    const float E10 = E01;                                                    \
    const float trm = m00 + m11;                                              \
    const float dev00 = m00 - 0.5f * trm;                                     \
    const float dev01 = m01;                                                  \
    const float dev10 = m10;                                                  \
    const float dev11 = m11 - 0.5f * trm;                                     \
    const float dmag_sq =                                                     \
        dev00 * dev00 + dev01 * dev01 + dev10 * dev10 + dev11 * dev11;        \
    const float dm = sqrtf(dmag_sq);                                          \
    const float dm2 = dm * dm;                                                \
    const float devE = dev00 * E00 + dev01 * E01 + dev10 * E10 + dev11 * E11; \
    const float sg = (devE > 0.f) ? 1.f : ((devE < 0.f) ? -1.f : 0.f);        \
    const float coef = sg * devE / dm2;                                       \
    const float sc = 0.5f * dm / m0;                                          \
    const float Ea00 = (E00 - coef * dev00) * sc;                             \
    const float Ea01 = (E01 - coef * dev01) * sc;                             \
    const float Ea10 = (E10 - coef * dev10) * sc;                             \
    const float Ea11 = (E11 - coef * dev11) * sc;                             \
    const float Ep00 = E00 - Ea00;                                            \
    const float Ep01 = E01 - Ea01;                                            \
    const float Ep10 = E10 - Ea10;                                            \
    const float Ep11 = E11 - Ea11;                                            \
    const float mE00 = (m00 * Ep00 + m01 * Ep10) + (Ep00 * m00 + Ep01 * m10); \
    const float mE01 = (m00 * Ep01 + m01 * Ep11) + (Ep00 * m01 + Ep01 * m11); \
    const float mE10 = (m10 * Ep00 + m11 * Ep10) + (Ep10 * m00 + Ep11 * m10); \
    const float mE11 = (m10 * Ep01 + m11 * Ep11) + (Ep10 * m01 + Ep11 * m11); \
    const float divv = gv00 + gv11;                                           \
    const float cdot =                                                        \
        -(v0 * dY_c + v1 * dX_c) - cad0 * c + cad1 * c * divv + cad2 * g;     \
    const float md00 = -(v0 * dY_m00 + v1 * dX_m00) - ww * m10 - ww * m01 -   \
                       my0 * m00 + my1 * mE00 - my2 * c * mE00 + my3 * trm +  \
                       my4 * trm * m00;                                       \
    const float md01 = -(v0 * dY_m01 + v1 * dX_m01) - ww * m11 + ww * m00 -   \
                       my0 * m01 + my1 * mE01 - my2 * c * mE01 +              \
                       my4 * trm * m01;                                       \
    const float md10 = -(v0 * dY_m10 + v1 * dX_m10) + ww * m00 - ww * m11 -   \
                       my0 * m10 + my1 * mE10 - my2 * c * mE10 +              \
                       my4 * trm * m10;                                       \
    const float md11 = -(v0 * dY_m11 + v1 * dX_m11) + ww * m01 + ww * m10 -   \
                       my0 * m11 + my1 * mE11 - my2 * c * mE11 +              \
                       my4 * trm * m11;                                       \
    out[idx] = md00;                                                          \
    out[idx + (size_t)NHW] = md01;                                            \
    out[idx + 2 * (size_t)NHW] = md10;                                        \
    out[idx + 3 * (size_t)NHW] = md11;                                        \
    out[idx + 4 * (size_t)NHW] = cdot;                                        \
  }

  POINT(0) POINT(1) POINT(2) POINT(3)
  POINT(4) POINT(5) POINT(6) POINT(7)
#undef POINT
}

extern "C" void kernel_launch(void* const* d_in, const int* in_sizes, int n_in,
                              void* d_out, int out_size, void* d_ws, size_t ws_size,
                              hipStream_t stream) {
  (void)in_sizes; (void)n_in; (void)out_size; (void)ws_size;
  const float* y = (const float*)d_in[0];
  const float* v = (const float*)d_in[1];
  const float* gds = (const float*)d_in[2];
  const float* cadc = (const float*)d_in[3];
  const float* myoc = (const float*)d_in[4];
  float* out = (float*)d_out;

  double* acc = (double*)d_ws;                       // 8B accumulator
  float* planes = (float*)((char*)d_ws + 512);       // 14 x NHW fp32 planes (7..13 used)

  hipMemsetAsync(acc, 0, sizeof(double), stream);
  k_reduce<<<dim3(1024), dim3(256), 0, stream>>>(y, acc);
  k_dx<<<dim3(NH, 7), dim3(256), 0, stream>>>(y, v, planes);
  k_dyf<<<dim3(NW / TW, NH / TH), dim3(256), 0, stream>>>(y, v, gds, cadc, myoc,
                                                          planes, acc, out);
}